// Round 1
// baseline (1829.054 us; speedup 1.0000x reference)
//
#include <hip/hip_runtime.h>

typedef _Float16 half2f __attribute__((ext_vector_type(2)));

#define HID 128   // hidden size
#define G4  512   // 4*HID
#define DIN 64    // input dim

__device__ __forceinline__ float fdot2(half2f a, half2f b, float c) {
  return __builtin_amdgcn_fdot2(a, b, c, false);
}
__device__ __forceinline__ half2f as_h2(unsigned int u) {
  return __builtin_bit_cast(half2f, u);
}
__device__ __forceinline__ half2f mk2(float a, float b) {
  half2f r; r.x = (_Float16)a; r.y = (_Float16)b; return r;
}
__device__ __forceinline__ float sigmoidf_fast(float x) {
  // robust: exp(-x)->inf => rcp(inf)=0 ; exp(-x)->0 => 1
  return __builtin_amdgcn_rcpf(1.0f + __expf(-x));
}
__device__ __forceinline__ float tanhf_fast(float x) {
  // tanh(x) = 2*sigmoid(2x)-1 ; robust at +-inf
  return 2.0f * __builtin_amdgcn_rcpf(1.0f + __expf(-2.0f * x)) - 1.0f;
}

// ---------------------------------------------------------------------------
// Phase 1: x_proj[r][g] = dot(input[r][:], W_ih[g][:]) + (b_ih[g]+b_hh[g])
// stored as fp16. r = b*T + t (input is (B,T,D) row-major so rows match).
// Thread = gate g (512 threads). W_ih row held in registers as fp16 pairs.
// 8 input rows staged in LDS per barrier pair, next chunk prefetched.
// ---------------------------------------------------------------------------
__global__ __launch_bounds__(512, 2)
void xproj_kernel(const float* __restrict__ x, const float* __restrict__ Wih,
                  const float* __restrict__ bih, const float* __restrict__ bhh,
                  _Float16* __restrict__ xp, int nrows)
{
  const int g = threadIdx.x;

  half2f wi[32];
  {
    const float4* wr = (const float4*)(Wih + (size_t)g * DIN);
#pragma unroll
    for (int q = 0; q < 16; q++) {
      float4 v = wr[q];
      wi[2 * q + 0] = mk2(v.x, v.y);
      wi[2 * q + 1] = mk2(v.z, v.w);
    }
  }
  const float bias = bih[g] + bhh[g];

  __shared__ __align__(16) _Float16 xin[8 * DIN];

  const int rows_per_block = (nrows + (int)gridDim.x - 1) / (int)gridDim.x;
  const int r0 = blockIdx.x * rows_per_block;
  const int r1 = (r0 + rows_per_block < nrows) ? (r0 + rows_per_block) : nrows;

  const int rsub = threadIdx.x >> 6;  // 0..7
  const int dd   = threadIdx.x & 63;

  float vld = 0.f;
  if (r0 + rsub < nrows) vld = x[(size_t)(r0 + rsub) * DIN + dd];

  for (int r = r0; r < r1; r += 8) {
    __syncthreads();                       // prev chunk reads done
    xin[rsub * DIN + dd] = (_Float16)vld;
    __syncthreads();
    // prefetch next chunk while computing this one
    int rn = r + 8 + rsub;
    if (rn < nrows) vld = x[(size_t)rn * DIN + dd];

    const uint4* xi4 = (const uint4*)xin;  // 8 uint4 per row (64 halves)
#pragma unroll
    for (int k = 0; k < 8; k++) {
      if (r + k >= r1) break;
      const uint4* row = xi4 + k * (DIN / 8);
      float a[4] = {bias, 0.f, 0.f, 0.f};
#pragma unroll
      for (int q = 0; q < 8; q++) {
        uint4 hv = row[q];
        a[q & 3] = fdot2(as_h2(hv.x), wi[4 * q + 0], a[q & 3]);
        a[q & 3] = fdot2(as_h2(hv.y), wi[4 * q + 1], a[q & 3]);
        a[q & 3] = fdot2(as_h2(hv.z), wi[4 * q + 2], a[q & 3]);
        a[q & 3] = fdot2(as_h2(hv.w), wi[4 * q + 3], a[q & 3]);
      }
      xp[(size_t)(r + k) * G4 + g] = (_Float16)(a[0] + a[1] + a[2] + a[3]);
    }
  }
}

// ---------------------------------------------------------------------------
// Phase 2: the recurrent scan. One block per batch element b (64 blocks,
// each on its own CU). Thread = gate g. W_hh row g in registers (64 half2).
// h broadcast via LDS (uniform-address ds_read_b128 -> conflict-free).
// Activations applied distributed (wave-uniform branch) before the LDS
// handoff; the 128-thread serial phase is only the c/h update.
// ---------------------------------------------------------------------------
template <bool PRECOMP>
__global__ __launch_bounds__(512, 2)
void lstm_scan(const float* __restrict__ x,    // (B,T,D)   [!PRECOMP]
               const float* __restrict__ Wih,  //           [!PRECOMP]
               const float* __restrict__ Whh,  // (4H,H)
               const float* __restrict__ bih, const float* __restrict__ bhh,
               const float* __restrict__ h0, const float* __restrict__ c0,
               const _Float16* __restrict__ xp,  //          [PRECOMP]
               float* __restrict__ out, int T)
{
  const int g = threadIdx.x;
  const int b = blockIdx.x;

  // W_hh row g -> 64 half2 in registers
  half2f w[64];
  {
    const float4* wr = (const float4*)(Whh + (size_t)g * HID);
#pragma unroll
    for (int q = 0; q < 32; q++) {
      float4 v = wr[q];
      w[2 * q + 0] = mk2(v.x, v.y);
      w[2 * q + 1] = mk2(v.z, v.w);
    }
  }

  half2f wi[PRECOMP ? 1 : 32];
  float bias = 0.f;
  if (!PRECOMP) {
    const float4* wr = (const float4*)(Wih + (size_t)g * DIN);
#pragma unroll
    for (int q = 0; q < 16; q++) {
      float4 v = wr[q];
      wi[(2 * q + 0) % 32] = mk2(v.x, v.y);
      wi[(2 * q + 1) % 32] = mk2(v.z, v.w);
    }
    bias = bih[g] + bhh[g];
  }

  __shared__ __align__(16) _Float16 h_sh[HID];
  __shared__ __align__(16) _Float16 xin[PRECOMP ? 4 : DIN];
  __shared__ float pre[G4];

  float c = 0.f;
  if (g < HID) {
    c = c0[(size_t)b * HID + g];
    h_sh[g] = (_Float16)h0[(size_t)b * HID + g];
  }
  if (!PRECOMP) {
    if (g < DIN) xin[g % (PRECOMP ? 4 : DIN)] = (_Float16)x[((size_t)b * T) * DIN + g];
  }
  __syncthreads();

  float xv_next = 0.f;
  if (PRECOMP) xv_next = (float)xp[((size_t)b * T) * G4 + g];

  const bool is_tanh_gate = (g >= 2 * HID) && (g < 3 * HID);  // wave-uniform

  for (int t = 0; t < T; ++t) {
    float xv = xv_next;
    if (PRECOMP && (t + 1 < T))
      xv_next = (float)xp[((size_t)b * T + (t + 1)) * G4 + g];

    // recurrent dot: 16x ds_read_b128 (broadcast) + 64 fdot2, 4 acc chains
    float a[4] = {0.f, 0.f, 0.f, 0.f};
    const uint4* h4 = (const uint4*)h_sh;
#pragma unroll
    for (int q = 0; q < 16; q++) {
      uint4 hv = h4[q];
      a[q & 3] = fdot2(as_h2(hv.x), w[4 * q + 0], a[q & 3]);
      a[q & 3] = fdot2(as_h2(hv.y), w[4 * q + 1], a[q & 3]);
      a[q & 3] = fdot2(as_h2(hv.z), w[4 * q + 2], a[q & 3]);
      a[q & 3] = fdot2(as_h2(hv.w), w[4 * q + 3], a[q & 3]);
    }
    if (!PRECOMP) {
      const uint4* x4 = (const uint4*)xin;
#pragma unroll
      for (int q = 0; q < 8; q++) {
        uint4 hv = x4[q];
        a[q & 3] = fdot2(as_h2(hv.x), wi[(4 * q + 0) % 32], a[q & 3]);
        a[q & 3] = fdot2(as_h2(hv.y), wi[(4 * q + 1) % 32], a[q & 3]);
        a[q & 3] = fdot2(as_h2(hv.z), wi[(4 * q + 2) % 32], a[q & 3]);
        a[q & 3] = fdot2(as_h2(hv.w), wi[(4 * q + 3) % 32], a[q & 3]);
      }
      xv = bias;
    }
    float preact = a[0] + a[1] + a[2] + a[3] + xv;
    // distributed activation (wave-uniform branch: gate-g block = waves 4,5)
    float act = is_tanh_gate ? tanhf_fast(preact) : sigmoidf_fast(preact);
    pre[g] = act;
    __syncthreads();

    if (g < HID) {
      float i  = pre[g];
      float f  = pre[g + HID];
      float gg = pre[g + 2 * HID];
      float o  = pre[g + 3 * HID];
      c = f * c + i * gg;
      float h = o * tanhf_fast(c);
      out[((size_t)b * T + t) * HID + g] = h;
      h_sh[g] = (_Float16)h;
    } else if (!PRECOMP && g >= HID && g < HID + DIN) {
      int d = g - HID;
      if (t + 1 < T)
        xin[d % (PRECOMP ? 4 : DIN)] = (_Float16)x[((size_t)b * T + (t + 1)) * DIN + d];
    }
    __syncthreads();
  }
}

// ---------------------------------------------------------------------------
extern "C" void kernel_launch(void* const* d_in, const int* in_sizes, int n_in,
                              void* d_out, int out_size, void* d_ws, size_t ws_size,
                              hipStream_t stream)
{
  const float* x   = (const float*)d_in[0];
  const float* Wih = (const float*)d_in[1];
  const float* Whh = (const float*)d_in[2];
  const float* bih = (const float*)d_in[3];
  const float* bhh = (const float*)d_in[4];
  const float* h0  = (const float*)d_in[5];
  const float* c0  = (const float*)d_in[6];
  float* out = (float*)d_out;

  const int B = in_sizes[5] / HID;          // h0 = (B,H)
  const int T = in_sizes[0] / (B * DIN);    // input = (B,T,D)
  const int nrows = B * T;

  const size_t xp_bytes = (size_t)nrows * G4 * sizeof(_Float16);
  const bool precomp = (ws_size >= xp_bytes);

  if (precomp) {
    _Float16* xp = (_Float16*)d_ws;
    xproj_kernel<<<512, 512, 0, stream>>>(x, Wih, bih, bhh, xp, nrows);
    lstm_scan<true><<<B, 512, 0, stream>>>(x, Wih, Whh, bih, bhh, h0, c0, xp, out, T);
  } else {
    lstm_scan<false><<<B, 512, 0, stream>>>(x, Wih, Whh, bih, bhh, h0, c0, nullptr, out, T);
  }
}

// Round 2
// 1049.768 us; speedup vs baseline: 1.7423x; 1.7423x over previous
//
#include <hip/hip_runtime.h>

typedef _Float16 half2f __attribute__((ext_vector_type(2)));

#define HID 128   // hidden size
#define G4  512   // 4*HID
#define DIN 64    // input dim

__device__ __forceinline__ float fdot2(half2f a, half2f b, float c) {
  return __builtin_amdgcn_fdot2(a, b, c, false);
}
__device__ __forceinline__ half2f as_h2(unsigned int u) {
  return __builtin_bit_cast(half2f, u);
}
__device__ __forceinline__ half2f mk2(float a, float b) {
  half2f r; r.x = (_Float16)a; r.y = (_Float16)b; return r;
}
__device__ __forceinline__ float sigmoidf_fast(float x) {
  return __builtin_amdgcn_rcpf(1.0f + __expf(-x));
}
__device__ __forceinline__ float tanhf_fast(float x) {
  return 2.0f * __builtin_amdgcn_rcpf(1.0f + __expf(-2.0f * x)) - 1.0f;
}
// add partner's (lane^1) value: DPP quad_perm [1,0,3,2] = 0xB1, VALU-only
__device__ __forceinline__ float dpp_xor1_add(float x) {
  int m = __builtin_amdgcn_update_dpp(0, __builtin_bit_cast(int, x),
                                      0xB1, 0xF, 0xF, true);
  return x + __builtin_bit_cast(float, m);
}

// ---------------------------------------------------------------------------
// Phase 1: x_proj, stored PERMUTED: element [r][unit*4 + gate] so that scan
// thread (j,kq) reads one u32 (gates 2kq,2kq+1 of unit j) per step, coalesced.
// Thread g_perm: unit = g_perm>>2, gate = g_perm&3, weight row = gate*128+unit.
// ---------------------------------------------------------------------------
__global__ __launch_bounds__(512, 2)
void xproj_kernel(const float* __restrict__ x, const float* __restrict__ Wih,
                  const float* __restrict__ bih, const float* __restrict__ bhh,
                  _Float16* __restrict__ xp, int nrows)
{
  const int gp   = threadIdx.x;          // permuted gate index
  const int unit = gp >> 2;
  const int gate = gp & 3;
  const int row  = gate * HID + unit;    // row in W_ih / bias

  half2f wi[32];
  {
    const float4* wr = (const float4*)(Wih + (size_t)row * DIN);
#pragma unroll
    for (int q = 0; q < 16; q++) {
      float4 v = wr[q];
      wi[2 * q + 0] = mk2(v.x, v.y);
      wi[2 * q + 1] = mk2(v.z, v.w);
    }
  }
  const float bias = bih[row] + bhh[row];

  __shared__ __align__(16) _Float16 xin[8 * DIN];

  const int rows_per_block = (nrows + (int)gridDim.x - 1) / (int)gridDim.x;
  const int r0 = blockIdx.x * rows_per_block;
  const int r1 = (r0 + rows_per_block < nrows) ? (r0 + rows_per_block) : nrows;

  const int rsub = threadIdx.x >> 6;  // 0..7
  const int dd   = threadIdx.x & 63;

  float vld = 0.f;
  if (r0 + rsub < nrows) vld = x[(size_t)(r0 + rsub) * DIN + dd];

  for (int r = r0; r < r1; r += 8) {
    __syncthreads();
    xin[rsub * DIN + dd] = (_Float16)vld;
    __syncthreads();
    int rn = r + 8 + rsub;
    if (rn < nrows) vld = x[(size_t)rn * DIN + dd];

    const uint4* xi4 = (const uint4*)xin;
#pragma unroll
    for (int k = 0; k < 8; k++) {
      if (r + k >= r1) break;
      const uint4* rowp = xi4 + k * (DIN / 8);
      float a[4] = {bias, 0.f, 0.f, 0.f};
#pragma unroll
      for (int q = 0; q < 8; q++) {
        uint4 hv = rowp[q];
        a[q & 3] = fdot2(as_h2(hv.x), wi[4 * q + 0], a[q & 3]);
        a[q & 3] = fdot2(as_h2(hv.y), wi[4 * q + 1], a[q & 3]);
        a[q & 3] = fdot2(as_h2(hv.z), wi[4 * q + 2], a[q & 3]);
        a[q & 3] = fdot2(as_h2(hv.w), wi[4 * q + 3], a[q & 3]);
      }
      xp[(size_t)(r + k) * G4 + gp] = (_Float16)(a[0] + a[1] + a[2] + a[3]);
    }
  }
}

// ---------------------------------------------------------------------------
// Phase 2: scan. 64 blocks x 256 threads (4 waves, 1/SIMD).
// Thread (j = tid>>1, kq = tid&1): computes all 4 gates of unit j over
// K-half kq. Pair-reduce via DPP xor1 add. One ds-roundtrip + one barrier
// per step (double-buffered h_sh). x_proj prefetched one step ahead.
// ---------------------------------------------------------------------------
__global__ __launch_bounds__(256, 1)
void lstm_scan2(const float* __restrict__ Whh,
                const float* __restrict__ h0, const float* __restrict__ c0,
                const _Float16* __restrict__ xp,
                float* __restrict__ out, int T)
{
  const int tid = threadIdx.x;
  const int j   = tid >> 1;
  const int kq  = tid & 1;
  const int b   = blockIdx.x;

  // W_hh rows gate*128+j, columns [64*kq, 64*kq+64) -> 4 x 32 half2
  half2f w0[32], w1[32], w2[32], w3[32];
  {
    const float4* r0 = (const float4*)(Whh + ((size_t)(0 * HID + j)) * HID + kq * 64);
    const float4* r1 = (const float4*)(Whh + ((size_t)(1 * HID + j)) * HID + kq * 64);
    const float4* r2 = (const float4*)(Whh + ((size_t)(2 * HID + j)) * HID + kq * 64);
    const float4* r3 = (const float4*)(Whh + ((size_t)(3 * HID + j)) * HID + kq * 64);
#pragma unroll
    for (int q = 0; q < 16; q++) {
      float4 v;
      v = r0[q]; w0[2 * q] = mk2(v.x, v.y); w0[2 * q + 1] = mk2(v.z, v.w);
      v = r1[q]; w1[2 * q] = mk2(v.x, v.y); w1[2 * q + 1] = mk2(v.z, v.w);
      v = r2[q]; w2[2 * q] = mk2(v.x, v.y); w2[2 * q + 1] = mk2(v.z, v.w);
      v = r3[q]; w3[2 * q] = mk2(v.x, v.y); w3[2 * q + 1] = mk2(v.z, v.w);
    }
  }

  __shared__ __align__(16) _Float16 h_sh[2][HID];

  float c = c0[(size_t)b * HID + j];
  if (kq == 0) h_sh[0][j] = (_Float16)h0[(size_t)b * HID + j];
  __syncthreads();

  const unsigned int* xp32 = (const unsigned int*)xp;   // u32 = 2 fp16 gates
  const size_t xbase = (size_t)b * T * 256 + (size_t)j * 2 + kq;
  unsigned int xv = xp32[xbase];

  const _Float16* rb = h_sh[0];
  _Float16*       wb = h_sh[1];

  for (int t = 0; t < T; ++t) {
    unsigned int xv_next = 0;
    if (t + 1 < T) xv_next = xp32[xbase + (size_t)(t + 1) * 256];

    // read my K-half of h: 8x ds_read_b128, all in flight at once
    uint4 hv[8];
    const uint4* h4 = (const uint4*)(rb + kq * 64);
#pragma unroll
    for (int q = 0; q < 8; q++) hv[q] = h4[q];

    float a0 = 0.f, a1 = 0.f, a2 = 0.f, a3 = 0.f;
#pragma unroll
    for (int q = 0; q < 8; q++) {
      unsigned int d0 = hv[q].x, d1 = hv[q].y, d2 = hv[q].z, d3 = hv[q].w;
      a0 = fdot2(as_h2(d0), w0[4 * q + 0], a0);
      a1 = fdot2(as_h2(d0), w1[4 * q + 0], a1);
      a2 = fdot2(as_h2(d0), w2[4 * q + 0], a2);
      a3 = fdot2(as_h2(d0), w3[4 * q + 0], a3);
      a0 = fdot2(as_h2(d1), w0[4 * q + 1], a0);
      a1 = fdot2(as_h2(d1), w1[4 * q + 1], a1);
      a2 = fdot2(as_h2(d1), w2[4 * q + 1], a2);
      a3 = fdot2(as_h2(d1), w3[4 * q + 1], a3);
      a0 = fdot2(as_h2(d2), w0[4 * q + 2], a0);
      a1 = fdot2(as_h2(d2), w1[4 * q + 2], a1);
      a2 = fdot2(as_h2(d2), w2[4 * q + 2], a2);
      a3 = fdot2(as_h2(d2), w3[4 * q + 2], a3);
      a0 = fdot2(as_h2(d3), w0[4 * q + 3], a0);
      a1 = fdot2(as_h2(d3), w1[4 * q + 3], a1);
      a2 = fdot2(as_h2(d3), w2[4 * q + 3], a2);
      a3 = fdot2(as_h2(d3), w3[4 * q + 3], a3);
    }

    // add x_proj: lane kq holds gates (2kq, 2kq+1) of unit j
    {
      half2f xh = as_h2(xv);
      float x0 = (float)xh.x, x1 = (float)xh.y;
      if (kq == 0) { a0 += x0; a1 += x1; }
      else         { a2 += x0; a3 += x1; }
    }

    // pair combine (K-half partials) via DPP — no LDS, no barrier
    a0 = dpp_xor1_add(a0);
    a1 = dpp_xor1_add(a1);
    a2 = dpp_xor1_add(a2);
    a3 = dpp_xor1_add(a3);

    float i  = sigmoidf_fast(a0);
    float f  = sigmoidf_fast(a1);
    float gg = tanhf_fast(a2);
    float o  = sigmoidf_fast(a3);
    c = f * c + i * gg;                 // c replicated on both lanes
    float h = o * tanhf_fast(c);

    if (kq == 0) {
      wb[j] = (_Float16)h;
      out[((size_t)b * T + t) * HID + j] = h;
    }
    __syncthreads();                    // single barrier per step
    const _Float16* tmp = rb; rb = wb; wb = (_Float16*)tmp;
    xv = xv_next;
  }
}

// ---------------------------------------------------------------------------
// Fallback (ws too small): proven round-1 kernel, computes x-proj inline.
// ---------------------------------------------------------------------------
__global__ __launch_bounds__(512, 2)
void lstm_scan_fb(const float* __restrict__ x, const float* __restrict__ Wih,
                  const float* __restrict__ Whh,
                  const float* __restrict__ bih, const float* __restrict__ bhh,
                  const float* __restrict__ h0, const float* __restrict__ c0,
                  float* __restrict__ out, int T)
{
  const int g = threadIdx.x;
  const int b = blockIdx.x;

  half2f w[64];
  {
    const float4* wr = (const float4*)(Whh + (size_t)g * HID);
#pragma unroll
    for (int q = 0; q < 32; q++) {
      float4 v = wr[q];
      w[2 * q + 0] = mk2(v.x, v.y);
      w[2 * q + 1] = mk2(v.z, v.w);
    }
  }
  half2f wi[32];
  float bias;
  {
    const float4* wr = (const float4*)(Wih + (size_t)g * DIN);
#pragma unroll
    for (int q = 0; q < 16; q++) {
      float4 v = wr[q];
      wi[2 * q + 0] = mk2(v.x, v.y);
      wi[2 * q + 1] = mk2(v.z, v.w);
    }
    bias = bih[g] + bhh[g];
  }

  __shared__ __align__(16) _Float16 h_sh[HID];
  __shared__ __align__(16) _Float16 xin[DIN];
  __shared__ float pre[G4];

  float c = 0.f;
  if (g < HID) {
    c = c0[(size_t)b * HID + g];
    h_sh[g] = (_Float16)h0[(size_t)b * HID + g];
  }
  if (g < DIN) xin[g] = (_Float16)x[((size_t)b * T) * DIN + g];
  __syncthreads();

  const bool is_tanh_gate = (g >= 2 * HID) && (g < 3 * HID);

  for (int t = 0; t < T; ++t) {
    float a[4] = {0.f, 0.f, 0.f, 0.f};
    const uint4* h4 = (const uint4*)h_sh;
#pragma unroll
    for (int q = 0; q < 16; q++) {
      uint4 hv = h4[q];
      a[q & 3] = fdot2(as_h2(hv.x), w[4 * q + 0], a[q & 3]);
      a[q & 3] = fdot2(as_h2(hv.y), w[4 * q + 1], a[q & 3]);
      a[q & 3] = fdot2(as_h2(hv.z), w[4 * q + 2], a[q & 3]);
      a[q & 3] = fdot2(as_h2(hv.w), w[4 * q + 3], a[q & 3]);
    }
    const uint4* x4 = (const uint4*)xin;
#pragma unroll
    for (int q = 0; q < 8; q++) {
      uint4 hv = x4[q];
      a[q & 3] = fdot2(as_h2(hv.x), wi[4 * q + 0], a[q & 3]);
      a[q & 3] = fdot2(as_h2(hv.y), wi[4 * q + 1], a[q & 3]);
      a[q & 3] = fdot2(as_h2(hv.z), wi[4 * q + 2], a[q & 3]);
      a[q & 3] = fdot2(as_h2(hv.w), wi[4 * q + 3], a[q & 3]);
    }
    float preact = a[0] + a[1] + a[2] + a[3] + bias;
    float act = is_tanh_gate ? tanhf_fast(preact) : sigmoidf_fast(preact);
    pre[g] = act;
    __syncthreads();

    if (g < HID) {
      float i  = pre[g];
      float f  = pre[g + HID];
      float gg = pre[g + 2 * HID];
      float o  = pre[g + 3 * HID];
      c = f * c + i * gg;
      float h = o * tanhf_fast(c);
      out[((size_t)b * T + t) * HID + g] = h;
      h_sh[g] = (_Float16)h;
    } else if (g >= HID && g < HID + DIN) {
      int d = g - HID;
      if (t + 1 < T) xin[d] = (_Float16)x[((size_t)b * T + (t + 1)) * DIN + d];
    }
    __syncthreads();
  }
}

// ---------------------------------------------------------------------------
extern "C" void kernel_launch(void* const* d_in, const int* in_sizes, int n_in,
                              void* d_out, int out_size, void* d_ws, size_t ws_size,
                              hipStream_t stream)
{
  const float* x   = (const float*)d_in[0];
  const float* Wih = (const float*)d_in[1];
  const float* Whh = (const float*)d_in[2];
  const float* bih = (const float*)d_in[3];
  const float* bhh = (const float*)d_in[4];
  const float* h0  = (const float*)d_in[5];
  const float* c0  = (const float*)d_in[6];
  float* out = (float*)d_out;

  const int B = in_sizes[5] / HID;
  const int T = in_sizes[0] / (B * DIN);
  const int nrows = B * T;

  const size_t xp_bytes = (size_t)nrows * G4 * sizeof(_Float16);
  if (ws_size >= xp_bytes) {
    _Float16* xp = (_Float16*)d_ws;
    xproj_kernel<<<1024, 512, 0, stream>>>(x, Wih, bih, bhh, xp, nrows);
    lstm_scan2<<<B, 256, 0, stream>>>(Whh, h0, c0, xp, out, T);
  } else {
    lstm_scan_fb<<<B, 512, 0, stream>>>(x, Wih, Whh, bih, bhh, h0, c0, out, T);
  }
}